// Round 3
// baseline (997.930 us; speedup 1.0000x reference)
//
#include <hip/hip_runtime.h>

#define N_NODES 50000
#define N_EDGES 800000
#define NB_SCAN 196   // ceil(N_NODES/256)

// ---------------- K1: histogram of destination degrees
__global__ void hist_kernel(const int* __restrict__ ei, int* __restrict__ counts) {
    int e = blockIdx.x * 256 + threadIdx.x;
    if (e < N_EDGES) atomicAdd(&counts[ei[N_EDGES + e]], 1);
}

// ---------------- K2a: per-block sums of counts
__global__ void scanA_kernel(const int* __restrict__ counts, int* __restrict__ bsum) {
    __shared__ int s[256];
    int i = blockIdx.x * 256 + threadIdx.x;
    s[threadIdx.x] = (i < N_NODES) ? counts[i] : 0;
    __syncthreads();
    for (int d = 128; d > 0; d >>= 1) {
        if (threadIdx.x < d) s[threadIdx.x] += s[threadIdx.x + d];
        __syncthreads();
    }
    if (threadIdx.x == 0) bsum[blockIdx.x] = s[0];
}

// ---------------- K2b: exclusive scan of block sums (1 block)
__global__ void scanB_kernel(const int* __restrict__ bsum, int* __restrict__ boff) {
    __shared__ int s[256];
    int tid = threadIdx.x;
    s[tid] = (tid < NB_SCAN) ? bsum[tid] : 0;
    __syncthreads();
    for (int d = 1; d < 256; d <<= 1) {
        int v = (tid >= d) ? s[tid - d] : 0;
        __syncthreads();
        s[tid] += v;
        __syncthreads();
    }
    if (tid < NB_SCAN) boff[tid] = (tid == 0) ? 0 : s[tid - 1];
}

// ---------------- K2c: per-element exclusive offsets
__global__ void scanC_kernel(const int* __restrict__ counts, const int* __restrict__ boff,
                             int* __restrict__ off, int* __restrict__ cursor) {
    __shared__ int s[256];
    int tid = threadIdx.x;
    int i = blockIdx.x * 256 + tid;
    int v = (i < N_NODES) ? counts[i] : 0;
    s[tid] = v;
    __syncthreads();
    for (int d = 1; d < 256; d <<= 1) {
        int t = (tid >= d) ? s[tid - d] : 0;
        __syncthreads();
        s[tid] += t;
        __syncthreads();
    }
    int excl = s[tid] - v + boff[blockIdx.x];
    if (i < N_NODES) { off[i] = excl; cursor[i] = excl; }
    if (i == 0) off[N_NODES] = N_EDGES;
}

// ---------------- K3: compute gaussian weights, scatter packed {src,w0,w1,w2} by dst
__global__ void scatter_kernel(const int* __restrict__ ei,
                               const float* __restrict__ pseudo,
                               const float* __restrict__ mu,
                               const float* __restrict__ sigma,
                               int* __restrict__ cursor,
                               float4* __restrict__ packed) {
    int e = blockIdx.x * 256 + threadIdx.x;
    if (e >= N_EDGES) return;
    const float mu0 = mu[0], mu1 = mu[1], mu2 = mu[2];
    const float s0 = sigma[0], s1 = sigma[1], s2 = sigma[2];
    const float c0 = -0.5f / (1e-14f + s0 * s0);
    const float c1 = -0.5f / (1e-14f + s1 * s1);
    const float c2 = -0.5f / (1e-14f + s2 * s2);
    const int s  = ei[e];
    const int dd = ei[N_EDGES + e];
    const float u = pseudo[e];
    const float d0 = u - mu0, d1 = u - mu1, d2 = u - mu2;
    const float w0 = expf(c0 * d0 * d0);
    const float w1 = expf(c1 * d1 * d1);
    const float w2 = expf(c2 * d2 * d2);
    const int pos = atomicAdd(&cursor[dd], 1);
    packed[pos] = make_float4(__int_as_float(s), w0, w1, w2);
}

// ---------------- K4: wave-per-node gather of RAW x rows -> agg[n][0:192], x copy in [192:256]
__global__ void aggregate_kernel(const float* __restrict__ x,
                                 const float4* __restrict__ packed,
                                 const int* __restrict__ off,
                                 float* __restrict__ aggm) {
    const int lane = threadIdx.x & 63;
    const int node = blockIdx.x * 4 + (threadIdx.x >> 6);
    if (node >= N_NODES) return;
    const int start = off[node], end = off[node + 1];
    float a0 = 0.f, a1 = 0.f, a2 = 0.f;
    int j = start;
    for (; j + 1 < end; j += 2) {
        const float4 p0 = packed[j];
        const float4 p1 = packed[j + 1];
        const float xv0 = x[(size_t)__float_as_int(p0.x) * 64 + lane];
        const float xv1 = x[(size_t)__float_as_int(p1.x) * 64 + lane];
        a0 += p0.y * xv0 + p1.y * xv1;
        a1 += p0.z * xv0 + p1.z * xv1;
        a2 += p0.w * xv0 + p1.w * xv1;
    }
    if (j < end) {
        const float4 p = packed[j];
        const float xv = x[(size_t)__float_as_int(p.x) * 64 + lane];
        a0 += p.y * xv; a1 += p.z * xv; a2 += p.w * xv;
    }
    const float inv = 1.0f / fmaxf((float)(end - start), 1.0f);
    float* row = aggm + (size_t)node * 256;
    row[lane]        = a0 * inv;
    row[64 + lane]   = a1 * inv;
    row[128 + lane]  = a2 * inv;
    row[192 + lane]  = x[(size_t)node * 64 + lane];   // for the fused x@root
}

// ---------------- K5: fused GEMM [50000,256]x[256,64] + bias + residual + silu
// W rows: rk<192 -> g[i=rk&63][ (rk>>6)*64 + d ]; rk>=192 -> root[rk-192][d]
#define FG_ROWS 128
__global__ void final_gemm_kernel(const float* __restrict__ aggm,
                                  const float* __restrict__ g,
                                  const float* __restrict__ root,
                                  const float* __restrict__ bias,
                                  float* __restrict__ out) {
    __shared__ float sW[64 * 64];         // [kk][c] for current K-chunk
    __shared__ float sIn[FG_ROWS * 68];   // [lr][kk], pad->68 for bank spread
    const int tid = threadIdx.x;
    const int cg = tid & 15;              // cols cg*4 .. cg*4+3
    const int rg = tid >> 4;              // rows rg + 16*r  (r=0..7)
    const int base = blockIdx.x * FG_ROWS;
    const int ld  = tid & 63;             // staging col
    const int lr0 = tid >> 6;             // staging row start (stride 4)

    float acc[8][4];
#pragma unroll
    for (int r = 0; r < 8; ++r)
#pragma unroll
        for (int c = 0; c < 4; ++c) acc[r][c] = 0.f;

    for (int chunk = 0; chunk < 4; ++chunk) {
        __syncthreads();
        // stage W chunk (coalesced over d)
#pragma unroll
        for (int it = 0; it < 16; ++it) {
            const int kk = lr0 + 4 * it;
            const int rk = chunk * 64 + kk;
            float w;
            if (rk < 192) w = g[(rk & 63) * 192 + (rk >> 6) * 64 + ld];
            else          w = root[(rk - 192) * 64 + ld];
            sW[kk * 64 + ld] = w;
        }
        // stage input chunk (coalesced over ld)
#pragma unroll
        for (int it = 0; it < 32; ++it) {
            const int lr = lr0 + 4 * it;
            int grow = base + lr;
            if (grow >= N_NODES) grow = N_NODES - 1;
            sIn[lr * 68 + ld] = aggm[(size_t)grow * 256 + chunk * 64 + ld];
        }
        __syncthreads();
#pragma unroll
        for (int step = 0; step < 16; ++step) {
            const int kk = step * 4;
            float4 a[8];
#pragma unroll
            for (int r = 0; r < 8; ++r)
                a[r] = *(const float4*)&sIn[(rg + 16 * r) * 68 + kk];
            float4 w[4];
#pragma unroll
            for (int c = 0; c < 4; ++c) {
                w[c].x = sW[(kk + 0) * 64 + cg * 4 + c];
                w[c].y = sW[(kk + 1) * 64 + cg * 4 + c];
                w[c].z = sW[(kk + 2) * 64 + cg * 4 + c];
                w[c].w = sW[(kk + 3) * 64 + cg * 4 + c];
            }
#pragma unroll
            for (int r = 0; r < 8; ++r)
#pragma unroll
                for (int c = 0; c < 4; ++c)
                    acc[r][c] += a[r].x * w[c].x + a[r].y * w[c].y
                               + a[r].z * w[c].z + a[r].w * w[c].w;
        }
    }
    // epilogue: + bias + residual(x) + silu, coalesced float4 store
    float b[4];
#pragma unroll
    for (int c = 0; c < 4; ++c) b[c] = bias[cg * 4 + c];
#pragma unroll
    for (int r = 0; r < 8; ++r) {
        const int grow = base + rg + 16 * r;
        if (grow < N_NODES) {
            const float4 xr = *(const float4*)&aggm[(size_t)grow * 256 + 192 + cg * 4];
            float xv[4] = {xr.x, xr.y, xr.z, xr.w};
            float4 o;
            float* op = &o.x;
#pragma unroll
            for (int c = 0; c < 4; ++c) {
                const float v = acc[r][c] + b[c] + xv[c];
                op[c] = v / (1.0f + expf(-v));
            }
            *(float4*)&out[(size_t)grow * 64 + cg * 4] = o;
        }
    }
}

extern "C" void kernel_launch(void* const* d_in, const int* in_sizes, int n_in,
                              void* d_out, int out_size, void* d_ws, size_t ws_size,
                              hipStream_t stream) {
    const float* x     = (const float*)d_in[0];
    const int*   ei    = (const int*)d_in[1];
    const float* ea    = (const float*)d_in[2];
    const float* g     = (const float*)d_in[3];
    const float* mu    = (const float*)d_in[4];
    const float* sigma = (const float*)d_in[5];
    const float* root  = (const float*)d_in[6];
    const float* bias  = (const float*)d_in[7];
    float* out = (float*)d_out;

    char* ws = (char*)d_ws;
    const size_t aggm_bytes   = (size_t)N_NODES * 256 * sizeof(float);  // 51.2 MB
    const size_t packed_bytes = (size_t)N_EDGES * sizeof(float4);       // 12.8 MB
    float*  aggm   = (float*)ws;
    float4* packed = (float4*)(ws + aggm_bytes);
    int* counts    = (int*)(ws + aggm_bytes + packed_bytes);
    int* off       = counts + N_NODES;          // N_NODES+1 entries
    int* cursor    = off + N_NODES + 1;
    int* bsum      = cursor + N_NODES;
    int* boff      = bsum + NB_SCAN;

    hipMemsetAsync(counts, 0, N_NODES * sizeof(int), stream);

    hist_kernel<<<(N_EDGES + 255) / 256, 256, 0, stream>>>(ei, counts);
    scanA_kernel<<<NB_SCAN, 256, 0, stream>>>(counts, bsum);
    scanB_kernel<<<1, 256, 0, stream>>>(bsum, boff);
    scanC_kernel<<<NB_SCAN, 256, 0, stream>>>(counts, boff, off, cursor);
    scatter_kernel<<<(N_EDGES + 255) / 256, 256, 0, stream>>>(ei, ea, mu, sigma, cursor, packed);
    aggregate_kernel<<<(N_NODES + 3) / 4, 256, 0, stream>>>(x, packed, off, aggm);
    final_gemm_kernel<<<(N_NODES + FG_ROWS - 1) / FG_ROWS, 256, 0, stream>>>(aggm, g, root, bias, out);
}

// Round 4
// 365.558 us; speedup vs baseline: 2.7299x; 2.7299x over previous
//
#include <hip/hip_runtime.h>

#define N_NODES 50000
#define N_EDGES 800000
#define NB_SCAN 196   // ceil(N_NODES/256)

// ---------------- K1: histogram of destination degrees
__global__ void hist_kernel(const int* __restrict__ ei, int* __restrict__ counts) {
    int e = blockIdx.x * 256 + threadIdx.x;
    if (e < N_EDGES) atomicAdd(&counts[ei[N_EDGES + e]], 1);
}

// ---------------- K2a: per-block sums of counts
__global__ void scanA_kernel(const int* __restrict__ counts, int* __restrict__ bsum) {
    __shared__ int s[256];
    int i = blockIdx.x * 256 + threadIdx.x;
    s[threadIdx.x] = (i < N_NODES) ? counts[i] : 0;
    __syncthreads();
    for (int d = 128; d > 0; d >>= 1) {
        if (threadIdx.x < d) s[threadIdx.x] += s[threadIdx.x + d];
        __syncthreads();
    }
    if (threadIdx.x == 0) bsum[blockIdx.x] = s[0];
}

// ---------------- K2b: exclusive scan of block sums (1 block)
__global__ void scanB_kernel(const int* __restrict__ bsum, int* __restrict__ boff) {
    __shared__ int s[256];
    int tid = threadIdx.x;
    s[tid] = (tid < NB_SCAN) ? bsum[tid] : 0;
    __syncthreads();
    for (int d = 1; d < 256; d <<= 1) {
        int v = (tid >= d) ? s[tid - d] : 0;
        __syncthreads();
        s[tid] += v;
        __syncthreads();
    }
    if (tid < NB_SCAN) boff[tid] = (tid == 0) ? 0 : s[tid - 1];
}

// ---------------- K2c: per-element exclusive offsets
__global__ void scanC_kernel(const int* __restrict__ counts, const int* __restrict__ boff,
                             int* __restrict__ off, int* __restrict__ cursor) {
    __shared__ int s[256];
    int tid = threadIdx.x;
    int i = blockIdx.x * 256 + tid;
    int v = (i < N_NODES) ? counts[i] : 0;
    s[tid] = v;
    __syncthreads();
    for (int d = 1; d < 256; d <<= 1) {
        int t = (tid >= d) ? s[tid - d] : 0;
        __syncthreads();
        s[tid] += t;
        __syncthreads();
    }
    int excl = s[tid] - v + boff[blockIdx.x];
    if (i < N_NODES) { off[i] = excl; cursor[i] = excl; }
    if (i == 0) off[N_NODES] = N_EDGES;
}

// ---------------- K3: compute gaussian weights, scatter packed {src,w0,w1,w2} by dst
__global__ void scatter_kernel(const int* __restrict__ ei,
                               const float* __restrict__ pseudo,
                               const float* __restrict__ mu,
                               const float* __restrict__ sigma,
                               int* __restrict__ cursor,
                               float4* __restrict__ packed) {
    int e = blockIdx.x * 256 + threadIdx.x;
    if (e >= N_EDGES) return;
    const float mu0 = mu[0], mu1 = mu[1], mu2 = mu[2];
    const float s0 = sigma[0], s1 = sigma[1], s2 = sigma[2];
    const float c0 = -0.5f / (1e-14f + s0 * s0);
    const float c1 = -0.5f / (1e-14f + s1 * s1);
    const float c2 = -0.5f / (1e-14f + s2 * s2);
    const int s  = ei[e];
    const int dd = ei[N_EDGES + e];
    const float u = pseudo[e];
    const float d0 = u - mu0, d1 = u - mu1, d2 = u - mu2;
    const float w0 = expf(c0 * d0 * d0);
    const float w1 = expf(c1 * d1 * d1);
    const float w2 = expf(c2 * d2 * d2);
    const int pos = atomicAdd(&cursor[dd], 1);
    packed[pos] = make_float4(__int_as_float(s), w0, w1, w2);
}

// ---------------- K4: wave-per-node gather of RAW x rows -> agg[n][0:192], x copy in [192:256]
__global__ void aggregate_kernel(const float* __restrict__ x,
                                 const float4* __restrict__ packed,
                                 const int* __restrict__ off,
                                 float* __restrict__ aggm) {
    const int lane = threadIdx.x & 63;
    const int node = blockIdx.x * 4 + (threadIdx.x >> 6);
    if (node >= N_NODES) return;
    const int start = off[node], end = off[node + 1];
    float a0 = 0.f, a1 = 0.f, a2 = 0.f;
    int j = start;
    for (; j + 1 < end; j += 2) {
        const float4 p0 = packed[j];
        const float4 p1 = packed[j + 1];
        const float xv0 = x[(size_t)__float_as_int(p0.x) * 64 + lane];
        const float xv1 = x[(size_t)__float_as_int(p1.x) * 64 + lane];
        a0 += p0.y * xv0 + p1.y * xv1;
        a1 += p0.z * xv0 + p1.z * xv1;
        a2 += p0.w * xv0 + p1.w * xv1;
    }
    if (j < end) {
        const float4 p = packed[j];
        const float xv = x[(size_t)__float_as_int(p.x) * 64 + lane];
        a0 += p.y * xv; a1 += p.z * xv; a2 += p.w * xv;
    }
    const float inv = 1.0f / fmaxf((float)(end - start), 1.0f);
    float* row = aggm + (size_t)node * 256;
    row[lane]        = a0 * inv;
    row[64 + lane]   = a1 * inv;
    row[128 + lane]  = a2 * inv;
    row[192 + lane]  = x[(size_t)node * 64 + lane];   // for the fused x@root
}

// ---------------- K5: fused GEMM [50000,256]x[256,64] + bias + residual + silu
// 64-row x 64-col block tile, 4x4 per thread (48 live floats -> no spill).
// W rows: rk<192 -> g[rk&63][(rk>>6)*64 + d]; rk>=192 -> root[rk-192][d]
__global__ __launch_bounds__(256, 2)
void final_gemm_kernel(const float* __restrict__ aggm,
                       const float* __restrict__ g,
                       const float* __restrict__ root,
                       const float* __restrict__ bias,
                       float* __restrict__ out) {
    __shared__ float sW[64 * 68];    // [kk][c], pad 68
    __shared__ float sIn[64 * 68];   // [lr][kk], pad 68
    const int tid = threadIdx.x;
    const int cg = tid & 15;         // cols cg*4 .. cg*4+3
    const int rg = tid >> 4;         // rows rg*4 .. rg*4+3
    const int base = blockIdx.x * 64;
    const int ld  = tid & 63;
    const int lr0 = tid >> 6;        // 0..3

    float acc[4][4];
#pragma unroll
    for (int r = 0; r < 4; ++r)
#pragma unroll
        for (int c = 0; c < 4; ++c) acc[r][c] = 0.f;

    for (int chunk = 0; chunk < 4; ++chunk) {
        __syncthreads();
        // stage W chunk (coalesced over d; conflict-free row-major write)
#pragma unroll
        for (int it = 0; it < 16; ++it) {
            const int kk = lr0 + 4 * it;
            const int rk = chunk * 64 + kk;
            float w;
            if (rk < 192) w = g[(rk & 63) * 192 + (rk >> 6) * 64 + ld];
            else          w = root[(rk - 192) * 64 + ld];
            sW[kk * 68 + ld] = w;
        }
        // stage input chunk (coalesced)
#pragma unroll
        for (int it = 0; it < 16; ++it) {
            const int lr = lr0 + 4 * it;
            int grow = base + lr;
            if (grow >= N_NODES) grow = N_NODES - 1;
            sIn[lr * 68 + ld] = aggm[(size_t)grow * 256 + chunk * 64 + ld];
        }
        __syncthreads();
#pragma unroll
        for (int step = 0; step < 16; ++step) {
            const int kk = step * 4;
            float4 a0 = *(const float4*)&sIn[(rg * 4 + 0) * 68 + kk];
            float4 a1 = *(const float4*)&sIn[(rg * 4 + 1) * 68 + kk];
            float4 a2 = *(const float4*)&sIn[(rg * 4 + 2) * 68 + kk];
            float4 a3 = *(const float4*)&sIn[(rg * 4 + 3) * 68 + kk];
            float4 w0 = *(const float4*)&sW[(kk + 0) * 68 + cg * 4];
            float4 w1 = *(const float4*)&sW[(kk + 1) * 68 + cg * 4];
            float4 w2 = *(const float4*)&sW[(kk + 2) * 68 + cg * 4];
            float4 w3 = *(const float4*)&sW[(kk + 3) * 68 + cg * 4];
            const float* ap[4] = {&a0.x, &a1.x, &a2.x, &a3.x};
            const float* wp[4] = {&w0.x, &w1.x, &w2.x, &w3.x};
#pragma unroll
            for (int r = 0; r < 4; ++r)
#pragma unroll
                for (int c = 0; c < 4; ++c)
                    acc[r][c] += ap[r][0] * wp[0][c] + ap[r][1] * wp[1][c]
                               + ap[r][2] * wp[2][c] + ap[r][3] * wp[3][c];
        }
    }
    // epilogue: + bias + residual(x) + silu, coalesced float4 store
    float b[4];
#pragma unroll
    for (int c = 0; c < 4; ++c) b[c] = bias[cg * 4 + c];
#pragma unroll
    for (int r = 0; r < 4; ++r) {
        const int grow = base + rg * 4 + r;
        if (grow < N_NODES) {
            const float4 xr = *(const float4*)&aggm[(size_t)grow * 256 + 192 + cg * 4];
            const float xv[4] = {xr.x, xr.y, xr.z, xr.w};
            float4 o;
            float* op = &o.x;
#pragma unroll
            for (int c = 0; c < 4; ++c) {
                const float v = acc[r][c] + b[c] + xv[c];
                op[c] = v / (1.0f + expf(-v));
            }
            *(float4*)&out[(size_t)grow * 64 + cg * 4] = o;
        }
    }
}

extern "C" void kernel_launch(void* const* d_in, const int* in_sizes, int n_in,
                              void* d_out, int out_size, void* d_ws, size_t ws_size,
                              hipStream_t stream) {
    const float* x     = (const float*)d_in[0];
    const int*   ei    = (const int*)d_in[1];
    const float* ea    = (const float*)d_in[2];
    const float* g     = (const float*)d_in[3];
    const float* mu    = (const float*)d_in[4];
    const float* sigma = (const float*)d_in[5];
    const float* root  = (const float*)d_in[6];
    const float* bias  = (const float*)d_in[7];
    float* out = (float*)d_out;

    char* ws = (char*)d_ws;
    const size_t aggm_bytes   = (size_t)N_NODES * 256 * sizeof(float);  // 51.2 MB
    const size_t packed_bytes = (size_t)N_EDGES * sizeof(float4);       // 12.8 MB
    float*  aggm   = (float*)ws;
    float4* packed = (float4*)(ws + aggm_bytes);
    int* counts    = (int*)(ws + aggm_bytes + packed_bytes);
    int* off       = counts + N_NODES;          // N_NODES+1 entries
    int* cursor    = off + N_NODES + 1;
    int* bsum      = cursor + N_NODES;
    int* boff      = bsum + NB_SCAN;

    hipMemsetAsync(counts, 0, N_NODES * sizeof(int), stream);

    hist_kernel<<<(N_EDGES + 255) / 256, 256, 0, stream>>>(ei, counts);
    scanA_kernel<<<NB_SCAN, 256, 0, stream>>>(counts, bsum);
    scanB_kernel<<<1, 256, 0, stream>>>(bsum, boff);
    scanC_kernel<<<NB_SCAN, 256, 0, stream>>>(counts, boff, off, cursor);
    scatter_kernel<<<(N_EDGES + 255) / 256, 256, 0, stream>>>(ei, ea, mu, sigma, cursor, packed);
    aggregate_kernel<<<(N_NODES + 3) / 4, 256, 0, stream>>>(x, packed, off, aggm);
    final_gemm_kernel<<<(N_NODES + 63) / 64, 256, 0, stream>>>(aggm, g, root, bias, out);
}

// Round 5
// 357.948 us; speedup vs baseline: 2.7879x; 1.0213x over previous
//
#include <hip/hip_runtime.h>

#define N_NODES 50000
#define N_EDGES 800000
#define NB_SCAN 196   // ceil(N_NODES/256)

// ---------------- K1: histogram of destination degrees
__global__ void hist_kernel(const int* __restrict__ ei, int* __restrict__ counts) {
    int e = blockIdx.x * 256 + threadIdx.x;
    if (e < N_EDGES) atomicAdd(&counts[ei[N_EDGES + e]], 1);
}

// ---------------- K2a: per-block sums of counts
__global__ void scanA_kernel(const int* __restrict__ counts, int* __restrict__ bsum) {
    __shared__ int s[256];
    int i = blockIdx.x * 256 + threadIdx.x;
    s[threadIdx.x] = (i < N_NODES) ? counts[i] : 0;
    __syncthreads();
    for (int d = 128; d > 0; d >>= 1) {
        if (threadIdx.x < d) s[threadIdx.x] += s[threadIdx.x + d];
        __syncthreads();
    }
    if (threadIdx.x == 0) bsum[blockIdx.x] = s[0];
}

// ---------------- K2b: exclusive scan of block sums (1 block)
__global__ void scanB_kernel(const int* __restrict__ bsum, int* __restrict__ boff) {
    __shared__ int s[256];
    int tid = threadIdx.x;
    s[tid] = (tid < NB_SCAN) ? bsum[tid] : 0;
    __syncthreads();
    for (int d = 1; d < 256; d <<= 1) {
        int v = (tid >= d) ? s[tid - d] : 0;
        __syncthreads();
        s[tid] += v;
        __syncthreads();
    }
    if (tid < NB_SCAN) boff[tid] = (tid == 0) ? 0 : s[tid - 1];
}

// ---------------- K2c: per-element exclusive offsets
__global__ void scanC_kernel(const int* __restrict__ counts, const int* __restrict__ boff,
                             int* __restrict__ off, int* __restrict__ cursor) {
    __shared__ int s[256];
    int tid = threadIdx.x;
    int i = blockIdx.x * 256 + tid;
    int v = (i < N_NODES) ? counts[i] : 0;
    s[tid] = v;
    __syncthreads();
    for (int d = 1; d < 256; d <<= 1) {
        int t = (tid >= d) ? s[tid - d] : 0;
        __syncthreads();
        s[tid] += t;
        __syncthreads();
    }
    int excl = s[tid] - v + boff[blockIdx.x];
    if (i < N_NODES) { off[i] = excl; cursor[i] = excl; }
    if (i == 0) off[N_NODES] = N_EDGES;
}

// ---------------- K3: compute gaussian weights, scatter packed {src,w0,w1,w2} by dst
__global__ void scatter_kernel(const int* __restrict__ ei,
                               const float* __restrict__ pseudo,
                               const float* __restrict__ mu,
                               const float* __restrict__ sigma,
                               int* __restrict__ cursor,
                               float4* __restrict__ packed) {
    int e = blockIdx.x * 256 + threadIdx.x;
    if (e >= N_EDGES) return;
    const float mu0 = mu[0], mu1 = mu[1], mu2 = mu[2];
    const float s0 = sigma[0], s1 = sigma[1], s2 = sigma[2];
    const float c0 = -0.5f / (1e-14f + s0 * s0);
    const float c1 = -0.5f / (1e-14f + s1 * s1);
    const float c2 = -0.5f / (1e-14f + s2 * s2);
    const int s  = ei[e];
    const int dd = ei[N_EDGES + e];
    const float u = pseudo[e];
    const float d0 = u - mu0, d1 = u - mu1, d2 = u - mu2;
    const float w0 = expf(c0 * d0 * d0);
    const float w1 = expf(c1 * d1 * d1);
    const float w2 = expf(c2 * d2 * d2);
    const int pos = atomicAdd(&cursor[dd], 1);
    packed[pos] = make_float4(__int_as_float(s), w0, w1, w2);
}

// ---------------- K4: wave-per-node gather of RAW x rows -> agg[n][0:192], x copy in [192:256]
__global__ void aggregate_kernel(const float* __restrict__ x,
                                 const float4* __restrict__ packed,
                                 const int* __restrict__ off,
                                 float* __restrict__ aggm) {
    const int lane = threadIdx.x & 63;
    const int node = blockIdx.x * 4 + (threadIdx.x >> 6);
    if (node >= N_NODES) return;
    const int start = off[node], end = off[node + 1];
    float a0 = 0.f, a1 = 0.f, a2 = 0.f;
    int j = start;
    for (; j + 1 < end; j += 2) {
        const float4 p0 = packed[j];
        const float4 p1 = packed[j + 1];
        const float xv0 = x[(size_t)__float_as_int(p0.x) * 64 + lane];
        const float xv1 = x[(size_t)__float_as_int(p1.x) * 64 + lane];
        a0 += p0.y * xv0 + p1.y * xv1;
        a1 += p0.z * xv0 + p1.z * xv1;
        a2 += p0.w * xv0 + p1.w * xv1;
    }
    if (j < end) {
        const float4 p = packed[j];
        const float xv = x[(size_t)__float_as_int(p.x) * 64 + lane];
        a0 += p.y * xv; a1 += p.z * xv; a2 += p.w * xv;
    }
    const float inv = 1.0f / fmaxf((float)(end - start), 1.0f);
    float* row = aggm + (size_t)node * 256;
    row[lane]        = a0 * inv;
    row[64 + lane]   = a1 * inv;
    row[128 + lane]  = a2 * inv;
    row[192 + lane]  = x[(size_t)node * 64 + lane];   // for the fused x@root
}

// ---------------- K5: fused GEMM [50000,256]x[256,64] + bias + residual + silu
// 64-row x 64-col block tile, 4x4 per thread. NO address-taken locals ->
// everything stays in VGPRs (round-4 spill was ap[]/wp[] pointer arrays).
#define FMA_ROW(r, ar)                                                   \
    acc[r][0] += ar.x * w0.x + ar.y * w1.x + ar.z * w2.x + ar.w * w3.x;  \
    acc[r][1] += ar.x * w0.y + ar.y * w1.y + ar.z * w2.y + ar.w * w3.y;  \
    acc[r][2] += ar.x * w0.z + ar.y * w1.z + ar.z * w2.z + ar.w * w3.z;  \
    acc[r][3] += ar.x * w0.w + ar.y * w1.w + ar.z * w2.w + ar.w * w3.w;

__global__ __launch_bounds__(256, 2)
void final_gemm_kernel(const float* __restrict__ aggm,
                       const float* __restrict__ g,
                       const float* __restrict__ root,
                       const float* __restrict__ bias,
                       float* __restrict__ out) {
    __shared__ float sW[64 * 68];    // [kk][c], pad 68
    __shared__ float sIn[64 * 68];   // [lr][kk], pad 68
    const int tid = threadIdx.x;
    const int cg = tid & 15;         // cols cg*4 .. cg*4+3
    const int rg = tid >> 4;         // rows rg*4 .. rg*4+3
    const int base = blockIdx.x * 64;
    const int ld  = tid & 63;
    const int lr0 = tid >> 6;        // 0..3

    float acc[4][4];
#pragma unroll
    for (int r = 0; r < 4; ++r)
#pragma unroll
        for (int c = 0; c < 4; ++c) acc[r][c] = 0.f;

    for (int chunk = 0; chunk < 4; ++chunk) {
        __syncthreads();
        // stage W chunk (coalesced over d; conflict-free row-major write)
#pragma unroll
        for (int it = 0; it < 16; ++it) {
            const int kk = lr0 + 4 * it;
            const int rk = chunk * 64 + kk;
            float w;
            if (rk < 192) w = g[(rk & 63) * 192 + (rk >> 6) * 64 + ld];
            else          w = root[(rk - 192) * 64 + ld];
            sW[kk * 68 + ld] = w;
        }
        // stage input chunk (coalesced)
#pragma unroll
        for (int it = 0; it < 16; ++it) {
            const int lr = lr0 + 4 * it;
            int grow = base + lr;
            if (grow >= N_NODES) grow = N_NODES - 1;
            sIn[lr * 68 + ld] = aggm[(size_t)grow * 256 + chunk * 64 + ld];
        }
        __syncthreads();
#pragma unroll
        for (int step = 0; step < 16; ++step) {
            const int kk = step * 4;
            const float4 a0 = *(const float4*)&sIn[(rg * 4 + 0) * 68 + kk];
            const float4 a1 = *(const float4*)&sIn[(rg * 4 + 1) * 68 + kk];
            const float4 a2 = *(const float4*)&sIn[(rg * 4 + 2) * 68 + kk];
            const float4 a3 = *(const float4*)&sIn[(rg * 4 + 3) * 68 + kk];
            const float4 w0 = *(const float4*)&sW[(kk + 0) * 68 + cg * 4];
            const float4 w1 = *(const float4*)&sW[(kk + 1) * 68 + cg * 4];
            const float4 w2 = *(const float4*)&sW[(kk + 2) * 68 + cg * 4];
            const float4 w3 = *(const float4*)&sW[(kk + 3) * 68 + cg * 4];
            FMA_ROW(0, a0)
            FMA_ROW(1, a1)
            FMA_ROW(2, a2)
            FMA_ROW(3, a3)
        }
    }
    // epilogue: + bias + residual(x) + silu, coalesced float4 store
    const float4 bv = *(const float4*)&bias[cg * 4];
#pragma unroll
    for (int r = 0; r < 4; ++r) {
        const int grow = base + rg * 4 + r;
        if (grow < N_NODES) {
            const float4 xr = *(const float4*)&aggm[(size_t)grow * 256 + 192 + cg * 4];
            float4 o;
            float v;
            v = acc[r][0] + bv.x + xr.x;  o.x = v / (1.0f + expf(-v));
            v = acc[r][1] + bv.y + xr.y;  o.y = v / (1.0f + expf(-v));
            v = acc[r][2] + bv.z + xr.z;  o.z = v / (1.0f + expf(-v));
            v = acc[r][3] + bv.w + xr.w;  o.w = v / (1.0f + expf(-v));
            *(float4*)&out[(size_t)grow * 64 + cg * 4] = o;
        }
    }
}

extern "C" void kernel_launch(void* const* d_in, const int* in_sizes, int n_in,
                              void* d_out, int out_size, void* d_ws, size_t ws_size,
                              hipStream_t stream) {
    const float* x     = (const float*)d_in[0];
    const int*   ei    = (const int*)d_in[1];
    const float* ea    = (const float*)d_in[2];
    const float* g     = (const float*)d_in[3];
    const float* mu    = (const float*)d_in[4];
    const float* sigma = (const float*)d_in[5];
    const float* root  = (const float*)d_in[6];
    const float* bias  = (const float*)d_in[7];
    float* out = (float*)d_out;

    char* ws = (char*)d_ws;
    const size_t aggm_bytes   = (size_t)N_NODES * 256 * sizeof(float);  // 51.2 MB
    const size_t packed_bytes = (size_t)N_EDGES * sizeof(float4);       // 12.8 MB
    float*  aggm   = (float*)ws;
    float4* packed = (float4*)(ws + aggm_bytes);
    int* counts    = (int*)(ws + aggm_bytes + packed_bytes);
    int* off       = counts + N_NODES;          // N_NODES+1 entries
    int* cursor    = off + N_NODES + 1;
    int* bsum      = cursor + N_NODES;
    int* boff      = bsum + NB_SCAN;

    hipMemsetAsync(counts, 0, N_NODES * sizeof(int), stream);

    hist_kernel<<<(N_EDGES + 255) / 256, 256, 0, stream>>>(ei, counts);
    scanA_kernel<<<NB_SCAN, 256, 0, stream>>>(counts, bsum);
    scanB_kernel<<<1, 256, 0, stream>>>(bsum, boff);
    scanC_kernel<<<NB_SCAN, 256, 0, stream>>>(counts, boff, off, cursor);
    scatter_kernel<<<(N_EDGES + 255) / 256, 256, 0, stream>>>(ei, ea, mu, sigma, cursor, packed);
    aggregate_kernel<<<(N_NODES + 3) / 4, 256, 0, stream>>>(x, packed, off, aggm);
    final_gemm_kernel<<<(N_NODES + 63) / 64, 256, 0, stream>>>(aggm, g, root, bias, out);
}

// Round 6
// 222.613 us; speedup vs baseline: 4.4828x; 1.6079x over previous
//
#include <hip/hip_runtime.h>

#define N_NODES 50000
#define N_EDGES 800000
#define NB_SCAN 196   // ceil(N_NODES/256)

// ---------------- K1: histogram of destination degrees
__global__ void hist_kernel(const int* __restrict__ ei, int* __restrict__ counts) {
    int e = blockIdx.x * 256 + threadIdx.x;
    if (e < N_EDGES) atomicAdd(&counts[ei[N_EDGES + e]], 1);
}

// ---------------- K2a: per-block sums of counts
__global__ void scanA_kernel(const int* __restrict__ counts, int* __restrict__ bsum) {
    __shared__ int s[256];
    int i = blockIdx.x * 256 + threadIdx.x;
    s[threadIdx.x] = (i < N_NODES) ? counts[i] : 0;
    __syncthreads();
    for (int d = 128; d > 0; d >>= 1) {
        if (threadIdx.x < d) s[threadIdx.x] += s[threadIdx.x + d];
        __syncthreads();
    }
    if (threadIdx.x == 0) bsum[blockIdx.x] = s[0];
}

// ---------------- K2b: exclusive scan of block sums (1 block)
__global__ void scanB_kernel(const int* __restrict__ bsum, int* __restrict__ boff) {
    __shared__ int s[256];
    int tid = threadIdx.x;
    s[tid] = (tid < NB_SCAN) ? bsum[tid] : 0;
    __syncthreads();
    for (int d = 1; d < 256; d <<= 1) {
        int v = (tid >= d) ? s[tid - d] : 0;
        __syncthreads();
        s[tid] += v;
        __syncthreads();
    }
    if (tid < NB_SCAN) boff[tid] = (tid == 0) ? 0 : s[tid - 1];
}

// ---------------- K2c: per-element exclusive offsets
__global__ void scanC_kernel(const int* __restrict__ counts, const int* __restrict__ boff,
                             int* __restrict__ off, int* __restrict__ cursor) {
    __shared__ int s[256];
    int tid = threadIdx.x;
    int i = blockIdx.x * 256 + tid;
    int v = (i < N_NODES) ? counts[i] : 0;
    s[tid] = v;
    __syncthreads();
    for (int d = 1; d < 256; d <<= 1) {
        int t = (tid >= d) ? s[tid - d] : 0;
        __syncthreads();
        s[tid] += t;
        __syncthreads();
    }
    int excl = s[tid] - v + boff[blockIdx.x];
    if (i < N_NODES) { off[i] = excl; cursor[i] = excl; }
    if (i == 0) off[N_NODES] = N_EDGES;
}

// ---------------- K3: compute gaussian weights, scatter packed {src,w0,w1,w2} by dst
__global__ void scatter_kernel(const int* __restrict__ ei,
                               const float* __restrict__ pseudo,
                               const float* __restrict__ mu,
                               const float* __restrict__ sigma,
                               int* __restrict__ cursor,
                               float4* __restrict__ packed) {
    int e = blockIdx.x * 256 + threadIdx.x;
    if (e >= N_EDGES) return;
    const float mu0 = mu[0], mu1 = mu[1], mu2 = mu[2];
    const float s0 = sigma[0], s1 = sigma[1], s2 = sigma[2];
    const float c0 = -0.5f / (1e-14f + s0 * s0);
    const float c1 = -0.5f / (1e-14f + s1 * s1);
    const float c2 = -0.5f / (1e-14f + s2 * s2);
    const int s  = ei[e];
    const int dd = ei[N_EDGES + e];
    const float u = pseudo[e];
    const float d0 = u - mu0, d1 = u - mu1, d2 = u - mu2;
    const float w0 = expf(c0 * d0 * d0);
    const float w1 = expf(c1 * d1 * d1);
    const float w2 = expf(c2 * d2 * d2);
    const int pos = atomicAdd(&cursor[dd], 1);
    packed[pos] = make_float4(__int_as_float(s), w0, w1, w2);
}

// ---------------- K4: wave-per-node gather of RAW x rows -> agg[n][0:192], x copy in [192:256]
__global__ void aggregate_kernel(const float* __restrict__ x,
                                 const float4* __restrict__ packed,
                                 const int* __restrict__ off,
                                 float* __restrict__ aggm) {
    const int lane = threadIdx.x & 63;
    const int node = blockIdx.x * 4 + (threadIdx.x >> 6);
    if (node >= N_NODES) return;
    const int start = off[node], end = off[node + 1];
    float a0 = 0.f, a1 = 0.f, a2 = 0.f;
    int j = start;
    for (; j + 1 < end; j += 2) {
        const float4 p0 = packed[j];
        const float4 p1 = packed[j + 1];
        const float xv0 = x[(size_t)__float_as_int(p0.x) * 64 + lane];
        const float xv1 = x[(size_t)__float_as_int(p1.x) * 64 + lane];
        a0 += p0.y * xv0 + p1.y * xv1;
        a1 += p0.z * xv0 + p1.z * xv1;
        a2 += p0.w * xv0 + p1.w * xv1;
    }
    if (j < end) {
        const float4 p = packed[j];
        const float xv = x[(size_t)__float_as_int(p.x) * 64 + lane];
        a0 += p.y * xv; a1 += p.z * xv; a2 += p.w * xv;
    }
    const float inv = 1.0f / fmaxf((float)(end - start), 1.0f);
    float* row = aggm + (size_t)node * 256;
    row[lane]        = a0 * inv;
    row[64 + lane]   = a1 * inv;
    row[128 + lane]  = a2 * inv;
    row[192 + lane]  = x[(size_t)node * 64 + lane];   // for the fused x@root
}

// ---------------- K5: wave-per-4-rows GEMV: out = silu(aggm[.,0:256] @ W + bias + res)
// W[k][d]: k<192 -> g[k&63][(k>>6)*64+d]; k>=192 -> root[k-192][d]
// W fully in LDS [256][64]; rows staged in wave-private LDS strip; no main-loop
// barriers; 8 scalar accumulators -> no spill possible.
#define K5_BLOCKS 512
__global__ __launch_bounds__(256)
void rowgemm_kernel(const float* __restrict__ aggm,
                    const float* __restrict__ g,
                    const float* __restrict__ root,
                    const float* __restrict__ bias,
                    float* __restrict__ out) {
    __shared__ float sW[256 * 64];      // 64 KB, [k][d]
    __shared__ float sRow[4][1024];     // 16 KB, per-wave 4-row staging
    const int tid  = threadIdx.x;
    const int lane = tid & 63;
    const int wid  = tid >> 6;

    for (int i = tid; i < 256 * 64; i += 256) {
        const int k = i >> 6, d = i & 63;
        sW[i] = (k < 192) ? g[(k & 63) * 192 + (k >> 6) * 64 + d]
                          : root[(k - 192) * 64 + d];
    }
    __syncthreads();

    const float bv = bias[lane];
    const int nGroups = N_NODES / 4;            // 12500
    const int nWaves  = K5_BLOCKS * 4;
    for (int grp = blockIdx.x * 4 + wid; grp < nGroups; grp += nWaves) {
        const int row0 = grp * 4;
        const float4 r0 = *(const float4*)&aggm[(size_t)(row0 + 0) * 256 + lane * 4];
        const float4 r1 = *(const float4*)&aggm[(size_t)(row0 + 1) * 256 + lane * 4];
        const float4 r2 = *(const float4*)&aggm[(size_t)(row0 + 2) * 256 + lane * 4];
        const float4 r3 = *(const float4*)&aggm[(size_t)(row0 + 3) * 256 + lane * 4];
        *(float4*)&sRow[wid][0 * 256 + lane * 4] = r0;
        *(float4*)&sRow[wid][1 * 256 + lane * 4] = r1;
        *(float4*)&sRow[wid][2 * 256 + lane * 4] = r2;
        *(float4*)&sRow[wid][3 * 256 + lane * 4] = r3;
        // same-wave LDS ops are in-order; compiler inserts lgkmcnt before reads

        float aA0 = 0.f, aB0 = 0.f, aA1 = 0.f, aB1 = 0.f;
        float aA2 = 0.f, aB2 = 0.f, aA3 = 0.f, aB3 = 0.f;
#pragma unroll 8
        for (int k4 = 0; k4 < 64; ++k4) {
            const float4 b0 = *(const float4*)&sRow[wid][0 * 256 + k4 * 4];
            const float4 b1 = *(const float4*)&sRow[wid][1 * 256 + k4 * 4];
            const float4 b2 = *(const float4*)&sRow[wid][2 * 256 + k4 * 4];
            const float4 b3 = *(const float4*)&sRow[wid][3 * 256 + k4 * 4];
            const float w0 = sW[(k4 * 4 + 0) * 64 + lane];
            const float w1 = sW[(k4 * 4 + 1) * 64 + lane];
            const float w2 = sW[(k4 * 4 + 2) * 64 + lane];
            const float w3 = sW[(k4 * 4 + 3) * 64 + lane];
            aA0 += b0.x * w0 + b0.z * w2;  aB0 += b0.y * w1 + b0.w * w3;
            aA1 += b1.x * w0 + b1.z * w2;  aB1 += b1.y * w1 + b1.w * w3;
            aA2 += b2.x * w0 + b2.z * w2;  aB2 += b2.y * w1 + b2.w * w3;
            aA3 += b3.x * w0 + b3.z * w2;  aB3 += b3.y * w1 + b3.w * w3;
        }
        float v;
        v = aA0 + aB0 + bv + sRow[wid][0 * 256 + 192 + lane];
        out[(size_t)(row0 + 0) * 64 + lane] = v / (1.0f + expf(-v));
        v = aA1 + aB1 + bv + sRow[wid][1 * 256 + 192 + lane];
        out[(size_t)(row0 + 1) * 64 + lane] = v / (1.0f + expf(-v));
        v = aA2 + aB2 + bv + sRow[wid][2 * 256 + 192 + lane];
        out[(size_t)(row0 + 2) * 64 + lane] = v / (1.0f + expf(-v));
        v = aA3 + aB3 + bv + sRow[wid][3 * 256 + 192 + lane];
        out[(size_t)(row0 + 3) * 64 + lane] = v / (1.0f + expf(-v));
    }
}

extern "C" void kernel_launch(void* const* d_in, const int* in_sizes, int n_in,
                              void* d_out, int out_size, void* d_ws, size_t ws_size,
                              hipStream_t stream) {
    const float* x     = (const float*)d_in[0];
    const int*   ei    = (const int*)d_in[1];
    const float* ea    = (const float*)d_in[2];
    const float* g     = (const float*)d_in[3];
    const float* mu    = (const float*)d_in[4];
    const float* sigma = (const float*)d_in[5];
    const float* root  = (const float*)d_in[6];
    const float* bias  = (const float*)d_in[7];
    float* out = (float*)d_out;

    char* ws = (char*)d_ws;
    const size_t aggm_bytes   = (size_t)N_NODES * 256 * sizeof(float);  // 51.2 MB
    const size_t packed_bytes = (size_t)N_EDGES * sizeof(float4);       // 12.8 MB
    float*  aggm   = (float*)ws;
    float4* packed = (float4*)(ws + aggm_bytes);
    int* counts    = (int*)(ws + aggm_bytes + packed_bytes);
    int* off       = counts + N_NODES;          // N_NODES+1 entries
    int* cursor    = off + N_NODES + 1;
    int* bsum      = cursor + N_NODES;
    int* boff      = bsum + NB_SCAN;

    hipMemsetAsync(counts, 0, N_NODES * sizeof(int), stream);

    hist_kernel<<<(N_EDGES + 255) / 256, 256, 0, stream>>>(ei, counts);
    scanA_kernel<<<NB_SCAN, 256, 0, stream>>>(counts, bsum);
    scanB_kernel<<<1, 256, 0, stream>>>(bsum, boff);
    scanC_kernel<<<NB_SCAN, 256, 0, stream>>>(counts, boff, off, cursor);
    scatter_kernel<<<(N_EDGES + 255) / 256, 256, 0, stream>>>(ei, ea, mu, sigma, cursor, packed);
    aggregate_kernel<<<(N_NODES + 3) / 4, 256, 0, stream>>>(x, packed, off, aggm);
    rowgemm_kernel<<<K5_BLOCKS, 256, 0, stream>>>(aggm, g, root, bias, out);
}

// Round 7
// 189.142 us; speedup vs baseline: 5.2761x; 1.1770x over previous
//
#include <hip/hip_runtime.h>

#define N_NODES 50000
#define N_EDGES 800000
#define NB_SCAN 196   // ceil(N_NODES/256)

// ---------------- K1: histogram of destination degrees + rank assignment
__global__ void hist_kernel(const int* __restrict__ ei, int* __restrict__ counts,
                            int* __restrict__ rank) {
    int e = blockIdx.x * 256 + threadIdx.x;
    if (e < N_EDGES) rank[e] = atomicAdd(&counts[ei[N_EDGES + e]], 1);
}

// ---------------- K2a: per-block sums of counts
__global__ void scanA_kernel(const int* __restrict__ counts, int* __restrict__ bsum) {
    __shared__ int s[256];
    int i = blockIdx.x * 256 + threadIdx.x;
    s[threadIdx.x] = (i < N_NODES) ? counts[i] : 0;
    __syncthreads();
    for (int d = 128; d > 0; d >>= 1) {
        if (threadIdx.x < d) s[threadIdx.x] += s[threadIdx.x + d];
        __syncthreads();
    }
    if (threadIdx.x == 0) bsum[blockIdx.x] = s[0];
}

// ---------------- K2b: exclusive scan of block sums (1 block)
__global__ void scanB_kernel(const int* __restrict__ bsum, int* __restrict__ boff) {
    __shared__ int s[256];
    int tid = threadIdx.x;
    s[tid] = (tid < NB_SCAN) ? bsum[tid] : 0;
    __syncthreads();
    for (int d = 1; d < 256; d <<= 1) {
        int v = (tid >= d) ? s[tid - d] : 0;
        __syncthreads();
        s[tid] += v;
        __syncthreads();
    }
    if (tid < NB_SCAN) boff[tid] = (tid == 0) ? 0 : s[tid - 1];
}

// ---------------- K2c: per-element exclusive offsets
__global__ void scanC_kernel(const int* __restrict__ counts, const int* __restrict__ boff,
                             int* __restrict__ off) {
    __shared__ int s[256];
    int tid = threadIdx.x;
    int i = blockIdx.x * 256 + tid;
    int v = (i < N_NODES) ? counts[i] : 0;
    s[tid] = v;
    __syncthreads();
    for (int d = 1; d < 256; d <<= 1) {
        int t = (tid >= d) ? s[tid - d] : 0;
        __syncthreads();
        s[tid] += t;
        __syncthreads();
    }
    int excl = s[tid] - v + boff[blockIdx.x];
    if (i < N_NODES) off[i] = excl;
    if (i == 0) off[N_NODES] = N_EDGES;
}

// ---------------- K3: scatter 8-byte {src, u} records to CSR positions (no atomics)
__global__ void scatter_kernel(const int* __restrict__ ei,
                               const float* __restrict__ pseudo,
                               const int* __restrict__ off,
                               const int* __restrict__ rank,
                               int2* __restrict__ packed) {
    int e = blockIdx.x * 256 + threadIdx.x;
    if (e >= N_EDGES) return;
    const int s  = ei[e];
    const int dd = ei[N_EDGES + e];
    const int pos = off[dd] + rank[e];
    packed[pos] = make_int2(s, __float_as_int(pseudo[e]));
}

// ---------------- K4: wave-per-node gather of x rows -> agg[n][0:192], x copy [192:256]
__global__ void aggregate_kernel(const float* __restrict__ x,
                                 const int2* __restrict__ packed,
                                 const int* __restrict__ off,
                                 const float* __restrict__ mu,
                                 const float* __restrict__ sigma,
                                 float* __restrict__ aggm) {
    const int lane = threadIdx.x & 63;
    const int node = blockIdx.x * 4 + (threadIdx.x >> 6);
    if (node >= N_NODES) return;
    const float mu0 = mu[0], mu1 = mu[1], mu2 = mu[2];
    const float s0 = sigma[0], s1 = sigma[1], s2 = sigma[2];
    const float c0 = -0.5f / (1e-14f + s0 * s0);
    const float c1 = -0.5f / (1e-14f + s1 * s1);
    const float c2 = -0.5f / (1e-14f + s2 * s2);
    const int start = off[node], end = off[node + 1];
    float a0 = 0.f, a1 = 0.f, a2 = 0.f;
    int j = start;
    for (; j + 1 < end; j += 2) {
        const int2 p0 = packed[j];
        const int2 p1 = packed[j + 1];
        const float u0 = __int_as_float(p0.y);
        const float u1 = __int_as_float(p1.y);
        const float xv0 = x[(size_t)p0.x * 64 + lane];
        const float xv1 = x[(size_t)p1.x * 64 + lane];
        const float e00 = u0 - mu0, e01 = u0 - mu1, e02 = u0 - mu2;
        const float e10 = u1 - mu0, e11 = u1 - mu1, e12 = u1 - mu2;
        a0 += __expf(c0 * e00 * e00) * xv0 + __expf(c0 * e10 * e10) * xv1;
        a1 += __expf(c1 * e01 * e01) * xv0 + __expf(c1 * e11 * e11) * xv1;
        a2 += __expf(c2 * e02 * e02) * xv0 + __expf(c2 * e12 * e12) * xv1;
    }
    if (j < end) {
        const int2 p = packed[j];
        const float u = __int_as_float(p.y);
        const float xv = x[(size_t)p.x * 64 + lane];
        const float e0 = u - mu0, e1 = u - mu1, e2 = u - mu2;
        a0 += __expf(c0 * e0 * e0) * xv;
        a1 += __expf(c1 * e1 * e1) * xv;
        a2 += __expf(c2 * e2 * e2) * xv;
    }
    const float inv = 1.0f / fmaxf((float)(end - start), 1.0f);
    float* row = aggm + (size_t)node * 256;
    row[lane]        = a0 * inv;
    row[64 + lane]   = a1 * inv;
    row[128 + lane]  = a2 * inv;
    row[192 + lane]  = x[(size_t)node * 64 + lane];   // for the fused x@root
}

// ---------------- K5: wave-per-4-rows GEMV with bf16-packed W in LDS (48 KB total
// -> 3 blocks/CU). out = silu(aggm[.,0:256] @ W + bias + residual).
// W[k][d]: k<192 -> g[k&63][(k>>6)*64+d]; k>=192 -> root[k-192][d]
#define K5_BLOCKS 768
__device__ __forceinline__ unsigned bf16_rne(float f) {
    unsigned u = __float_as_uint(f);
    return (u + 0x7FFFu + ((u >> 16) & 1u)) >> 16;
}
__global__ __launch_bounds__(256)
void rowgemm_kernel(const float* __restrict__ aggm,
                    const float* __restrict__ g,
                    const float* __restrict__ root,
                    const float* __restrict__ bias,
                    float* __restrict__ out) {
    __shared__ unsigned sWp[128 * 64];  // 32 KB: k-pair kp -> {bf16 W[2kp], W[2kp+1]}
    __shared__ float sRow[4][1024];     // 16 KB, per-wave 4-row staging
    const int tid  = threadIdx.x;
    const int lane = tid & 63;
    const int wid  = tid >> 6;

    for (int i = tid; i < 128 * 64; i += 256) {
        const int kp = i >> 6, d = i & 63;
        const int k0 = kp * 2, k1 = kp * 2 + 1;
        const float w0 = (k0 < 192) ? g[(k0 & 63) * 192 + (k0 >> 6) * 64 + d]
                                    : root[(k0 - 192) * 64 + d];
        const float w1 = (k1 < 192) ? g[(k1 & 63) * 192 + (k1 >> 6) * 64 + d]
                                    : root[(k1 - 192) * 64 + d];
        sWp[i] = bf16_rne(w0) | (bf16_rne(w1) << 16);
    }
    __syncthreads();

    const float bv = bias[lane];
    const int nGroups = N_NODES / 4;            // 12500
    const int nWaves  = K5_BLOCKS * 4;
    for (int grp = blockIdx.x * 4 + wid; grp < nGroups; grp += nWaves) {
        const int row0 = grp * 4;
        const float4 r0 = *(const float4*)&aggm[(size_t)(row0 + 0) * 256 + lane * 4];
        const float4 r1 = *(const float4*)&aggm[(size_t)(row0 + 1) * 256 + lane * 4];
        const float4 r2 = *(const float4*)&aggm[(size_t)(row0 + 2) * 256 + lane * 4];
        const float4 r3 = *(const float4*)&aggm[(size_t)(row0 + 3) * 256 + lane * 4];
        *(float4*)&sRow[wid][0 * 256 + lane * 4] = r0;
        *(float4*)&sRow[wid][1 * 256 + lane * 4] = r1;
        *(float4*)&sRow[wid][2 * 256 + lane * 4] = r2;
        *(float4*)&sRow[wid][3 * 256 + lane * 4] = r3;
        // same-wave LDS ops are in-order; compiler inserts lgkmcnt before reads

        float aA0 = 0.f, aB0 = 0.f, aA1 = 0.f, aB1 = 0.f;
        float aA2 = 0.f, aB2 = 0.f, aA3 = 0.f, aB3 = 0.f;
#pragma unroll 8
        for (int k4 = 0; k4 < 64; ++k4) {
            const float4 b0 = *(const float4*)&sRow[wid][0 * 256 + k4 * 4];
            const float4 b1 = *(const float4*)&sRow[wid][1 * 256 + k4 * 4];
            const float4 b2 = *(const float4*)&sRow[wid][2 * 256 + k4 * 4];
            const float4 b3 = *(const float4*)&sRow[wid][3 * 256 + k4 * 4];
            const unsigned p01 = sWp[(k4 * 2 + 0) * 64 + lane];
            const unsigned p23 = sWp[(k4 * 2 + 1) * 64 + lane];
            const float w0 = __uint_as_float(p01 << 16);
            const float w1 = __uint_as_float(p01 & 0xFFFF0000u);
            const float w2 = __uint_as_float(p23 << 16);
            const float w3 = __uint_as_float(p23 & 0xFFFF0000u);
            aA0 += b0.x * w0 + b0.z * w2;  aB0 += b0.y * w1 + b0.w * w3;
            aA1 += b1.x * w0 + b1.z * w2;  aB1 += b1.y * w1 + b1.w * w3;
            aA2 += b2.x * w0 + b2.z * w2;  aB2 += b2.y * w1 + b2.w * w3;
            aA3 += b3.x * w0 + b3.z * w2;  aB3 += b3.y * w1 + b3.w * w3;
        }
        float v;
        v = aA0 + aB0 + bv + sRow[wid][0 * 256 + 192 + lane];
        out[(size_t)(row0 + 0) * 64 + lane] = v / (1.0f + expf(-v));
        v = aA1 + aB1 + bv + sRow[wid][1 * 256 + 192 + lane];
        out[(size_t)(row0 + 1) * 64 + lane] = v / (1.0f + expf(-v));
        v = aA2 + aB2 + bv + sRow[wid][2 * 256 + 192 + lane];
        out[(size_t)(row0 + 2) * 64 + lane] = v / (1.0f + expf(-v));
        v = aA3 + aB3 + bv + sRow[wid][3 * 256 + 192 + lane];
        out[(size_t)(row0 + 3) * 64 + lane] = v / (1.0f + expf(-v));
    }
}

extern "C" void kernel_launch(void* const* d_in, const int* in_sizes, int n_in,
                              void* d_out, int out_size, void* d_ws, size_t ws_size,
                              hipStream_t stream) {
    const float* x     = (const float*)d_in[0];
    const int*   ei    = (const int*)d_in[1];
    const float* ea    = (const float*)d_in[2];
    const float* g     = (const float*)d_in[3];
    const float* mu    = (const float*)d_in[4];
    const float* sigma = (const float*)d_in[5];
    const float* root  = (const float*)d_in[6];
    const float* bias  = (const float*)d_in[7];
    float* out = (float*)d_out;

    char* ws = (char*)d_ws;
    const size_t aggm_bytes   = (size_t)N_NODES * 256 * sizeof(float);  // 51.2 MB
    const size_t packed_bytes = (size_t)N_EDGES * sizeof(int2);         //  6.4 MB
    const size_t rank_bytes   = (size_t)N_EDGES * sizeof(int);          //  3.2 MB
    float* aggm   = (float*)ws;
    int2*  packed = (int2*)(ws + aggm_bytes);
    int*   rank   = (int*)(ws + aggm_bytes + packed_bytes);
    int*   counts = (int*)(ws + aggm_bytes + packed_bytes + rank_bytes);
    int*   off    = counts + N_NODES;           // N_NODES+1 entries
    int*   bsum   = off + N_NODES + 1;
    int*   boff   = bsum + NB_SCAN;

    hipMemsetAsync(counts, 0, N_NODES * sizeof(int), stream);

    hist_kernel<<<(N_EDGES + 255) / 256, 256, 0, stream>>>(ei, counts, rank);
    scanA_kernel<<<NB_SCAN, 256, 0, stream>>>(counts, bsum);
    scanB_kernel<<<1, 256, 0, stream>>>(bsum, boff);
    scanC_kernel<<<NB_SCAN, 256, 0, stream>>>(counts, boff, off);
    scatter_kernel<<<(N_EDGES + 255) / 256, 256, 0, stream>>>(ei, ea, off, rank, packed);
    aggregate_kernel<<<(N_NODES + 3) / 4, 256, 0, stream>>>(x, packed, off, mu, sigma, aggm);
    rowgemm_kernel<<<K5_BLOCKS, 256, 0, stream>>>(aggm, g, root, bias, out);
}

// Round 8
// 134.633 us; speedup vs baseline: 7.4122x; 1.4049x over previous
//
#include <hip/hip_runtime.h>

#define N_NODES 50000
#define N_EDGES 800000
#define NB_SCAN 196   // ceil(N_NODES/256)

typedef _Float16 f16x8 __attribute__((ext_vector_type(8)));
typedef float    f32x4 __attribute__((ext_vector_type(4)));

// ---------------- K1: histogram of destination degrees + rank assignment
__global__ void hist_kernel(const int* __restrict__ ei, int* __restrict__ counts,
                            int* __restrict__ rank) {
    int e = blockIdx.x * 256 + threadIdx.x;
    if (e < N_EDGES) rank[e] = atomicAdd(&counts[ei[N_EDGES + e]], 1);
}

// ---------------- K2a: per-block sums of counts
__global__ void scanA_kernel(const int* __restrict__ counts, int* __restrict__ bsum) {
    __shared__ int s[256];
    int i = blockIdx.x * 256 + threadIdx.x;
    s[threadIdx.x] = (i < N_NODES) ? counts[i] : 0;
    __syncthreads();
    for (int d = 128; d > 0; d >>= 1) {
        if (threadIdx.x < d) s[threadIdx.x] += s[threadIdx.x + d];
        __syncthreads();
    }
    if (threadIdx.x == 0) bsum[blockIdx.x] = s[0];
}

// ---------------- K2b: exclusive scan of block sums (1 block)
__global__ void scanB_kernel(const int* __restrict__ bsum, int* __restrict__ boff) {
    __shared__ int s[256];
    int tid = threadIdx.x;
    s[tid] = (tid < NB_SCAN) ? bsum[tid] : 0;
    __syncthreads();
    for (int d = 1; d < 256; d <<= 1) {
        int v = (tid >= d) ? s[tid - d] : 0;
        __syncthreads();
        s[tid] += v;
        __syncthreads();
    }
    if (tid < NB_SCAN) boff[tid] = (tid == 0) ? 0 : s[tid - 1];
}

// ---------------- K2c: per-element exclusive offsets
__global__ void scanC_kernel(const int* __restrict__ counts, const int* __restrict__ boff,
                             int* __restrict__ off) {
    __shared__ int s[256];
    int tid = threadIdx.x;
    int i = blockIdx.x * 256 + tid;
    int v = (i < N_NODES) ? counts[i] : 0;
    s[tid] = v;
    __syncthreads();
    for (int d = 1; d < 256; d <<= 1) {
        int t = (tid >= d) ? s[tid - d] : 0;
        __syncthreads();
        s[tid] += t;
        __syncthreads();
    }
    int excl = s[tid] - v + boff[blockIdx.x];
    if (i < N_NODES) off[i] = excl;
    if (i == 0) off[N_NODES] = N_EDGES;
}

// ---------------- K3: scatter 8-byte {src, u} records to CSR positions (no atomics)
__global__ void scatter_kernel(const int* __restrict__ ei,
                               const float* __restrict__ pseudo,
                               const int* __restrict__ off,
                               const int* __restrict__ rank,
                               int2* __restrict__ packed) {
    int e = blockIdx.x * 256 + threadIdx.x;
    if (e >= N_EDGES) return;
    const int s  = ei[e];
    const int dd = ei[N_EDGES + e];
    const int pos = off[dd] + rank[e];
    packed[pos] = make_int2(s, __float_as_int(pseudo[e]));
}

// ---------------- K4: wave-per-node gather of x rows -> fp16 agg[n][0:192], x copy [192:256]
__global__ void aggregate_kernel(const float* __restrict__ x,
                                 const int2* __restrict__ packed,
                                 const int* __restrict__ off,
                                 const float* __restrict__ mu,
                                 const float* __restrict__ sigma,
                                 _Float16* __restrict__ aggmh) {
    const int lane = threadIdx.x & 63;
    const int node = blockIdx.x * 4 + (threadIdx.x >> 6);
    if (node >= N_NODES) return;
    const float mu0 = mu[0], mu1 = mu[1], mu2 = mu[2];
    const float s0 = sigma[0], s1 = sigma[1], s2 = sigma[2];
    const float c0 = -0.5f / (1e-14f + s0 * s0);
    const float c1 = -0.5f / (1e-14f + s1 * s1);
    const float c2 = -0.5f / (1e-14f + s2 * s2);
    const int start = off[node], end = off[node + 1];
    float a0 = 0.f, a1 = 0.f, a2 = 0.f;
    int j = start;
    for (; j + 1 < end; j += 2) {
        const int2 p0 = packed[j];
        const int2 p1 = packed[j + 1];
        const float u0 = __int_as_float(p0.y);
        const float u1 = __int_as_float(p1.y);
        const float xv0 = x[(size_t)p0.x * 64 + lane];
        const float xv1 = x[(size_t)p1.x * 64 + lane];
        const float e00 = u0 - mu0, e01 = u0 - mu1, e02 = u0 - mu2;
        const float e10 = u1 - mu0, e11 = u1 - mu1, e12 = u1 - mu2;
        a0 += __expf(c0 * e00 * e00) * xv0 + __expf(c0 * e10 * e10) * xv1;
        a1 += __expf(c1 * e01 * e01) * xv0 + __expf(c1 * e11 * e11) * xv1;
        a2 += __expf(c2 * e02 * e02) * xv0 + __expf(c2 * e12 * e12) * xv1;
    }
    if (j < end) {
        const int2 p = packed[j];
        const float u = __int_as_float(p.y);
        const float xv = x[(size_t)p.x * 64 + lane];
        const float e0 = u - mu0, e1 = u - mu1, e2 = u - mu2;
        a0 += __expf(c0 * e0 * e0) * xv;
        a1 += __expf(c1 * e1 * e1) * xv;
        a2 += __expf(c2 * e2 * e2) * xv;
    }
    const float inv = 1.0f / fmaxf((float)(end - start), 1.0f);
    _Float16* row = aggmh + (size_t)node * 256;
    row[lane]       = (_Float16)(a0 * inv);
    row[64 + lane]  = (_Float16)(a1 * inv);
    row[128 + lane] = (_Float16)(a2 * inv);
    row[192 + lane] = (_Float16)x[(size_t)node * 64 + lane];   // for the fused x@root
}

// ---------------- K5a: pre-pack W into MFMA B-fragment layout (fp16)
// W[k][d]: k<192 -> g[k&63][(k>>6)*64+d]; k>=192 -> root[k-192][d]
// wfrag[((kc*4+c)*64 + lane)*8 + i] = f16(W[kc*32 + 8*(lane>>4) + i][c*16 + (lane&15)])
__global__ void wprep_kernel(const float* __restrict__ g,
                             const float* __restrict__ root,
                             _Float16* __restrict__ wfrag) {
    const int t = blockIdx.x * 256 + threadIdx.x;
    if (t >= 2048) return;
    const int lane = t & 63;
    const int cc   = (t >> 6) & 3;
    const int kc   = t >> 8;
    const int d     = cc * 16 + (lane & 15);
    const int kbase = kc * 32 + (lane >> 4) * 8;
    f16x8 v;
#pragma unroll
    for (int i = 0; i < 8; ++i) {
        const int k = kbase + i;
        const float w = (k < 192) ? g[(k & 63) * 192 + (k >> 6) * 64 + d]
                                  : root[(k - 192) * 64 + d];
        v[i] = (_Float16)w;
    }
    *(f16x8*)&wfrag[(size_t)t * 8] = v;
}

// ---------------- K5b: MFMA GEMM [50000,256]x[256,64] + bias + fp32 residual + silu
// wave = 16 rows x 64 cols (4 col-tiles of 16x16, K=256 -> 8 MFMA each)
#define BF(kc, c) (*(const f16x8*)&sWf[((((kc) * 4 + (c)) * 64 + lane) * 8)])
#define MFMA16(a, b, c) __builtin_amdgcn_mfma_f32_16x16x32_f16(a, b, c, 0, 0, 0)
#define COLTILE(c, accv)                                   \
    accv = MFMA16(af0, BF(0, c), accv);                    \
    accv = MFMA16(af1, BF(1, c), accv);                    \
    accv = MFMA16(af2, BF(2, c), accv);                    \
    accv = MFMA16(af3, BF(3, c), accv);                    \
    accv = MFMA16(af4, BF(4, c), accv);                    \
    accv = MFMA16(af5, BF(5, c), accv);                    \
    accv = MFMA16(af6, BF(6, c), accv);                    \
    accv = MFMA16(af7, BF(7, c), accv);
#define EPILOG(c, accv)                                                        \
    {                                                                          \
        const int col = (c) * 16 + (lane & 15);                                \
        const float bv = bias[col];                                            \
        _Pragma("unroll")                                                      \
        for (int r = 0; r < 4; ++r) {                                          \
            const int rr = orow + r;                                           \
            const float v = accv[r] + bv + x[(size_t)rr * 64 + col];           \
            out[(size_t)rr * 64 + col] = v / (1.0f + expf(-v));                \
        }                                                                      \
    }

__global__ __launch_bounds__(256)
void mfma_gemm_kernel(const _Float16* __restrict__ aggmh,
                      const _Float16* __restrict__ wfrag,
                      const float* __restrict__ x,
                      const float* __restrict__ bias,
                      float* __restrict__ out) {
    __shared__ _Float16 sWf[2048 * 8];   // 32 KB: full W in fragment layout
    const int tid = threadIdx.x;
    for (int i = tid; i < 2048; i += 256)
        *(f16x8*)&sWf[i * 8] = *(const f16x8*)&wfrag[(size_t)i * 8];
    __syncthreads();

    const int lane = tid & 63;
    const int wid  = tid >> 6;
    const int row0 = blockIdx.x * 64 + wid * 16;
    if (row0 >= N_NODES) return;   // 50000 % 16 == 0, so valid waves are fully valid

    const size_t abase = (size_t)(row0 + (lane & 15)) * 256 + (lane >> 4) * 8;
    const f16x8 af0 = *(const f16x8*)&aggmh[abase + 0 * 32];
    const f16x8 af1 = *(const f16x8*)&aggmh[abase + 1 * 32];
    const f16x8 af2 = *(const f16x8*)&aggmh[abase + 2 * 32];
    const f16x8 af3 = *(const f16x8*)&aggmh[abase + 3 * 32];
    const f16x8 af4 = *(const f16x8*)&aggmh[abase + 4 * 32];
    const f16x8 af5 = *(const f16x8*)&aggmh[abase + 5 * 32];
    const f16x8 af6 = *(const f16x8*)&aggmh[abase + 6 * 32];
    const f16x8 af7 = *(const f16x8*)&aggmh[abase + 7 * 32];

    f32x4 acc0 = {0.f, 0.f, 0.f, 0.f};
    f32x4 acc1 = {0.f, 0.f, 0.f, 0.f};
    f32x4 acc2 = {0.f, 0.f, 0.f, 0.f};
    f32x4 acc3 = {0.f, 0.f, 0.f, 0.f};
    COLTILE(0, acc0)
    COLTILE(1, acc1)
    COLTILE(2, acc2)
    COLTILE(3, acc3)

    const int orow = row0 + (lane >> 4) * 4;   // D: col=lane&15, row=(lane>>4)*4+reg
    EPILOG(0, acc0)
    EPILOG(1, acc1)
    EPILOG(2, acc2)
    EPILOG(3, acc3)
}

extern "C" void kernel_launch(void* const* d_in, const int* in_sizes, int n_in,
                              void* d_out, int out_size, void* d_ws, size_t ws_size,
                              hipStream_t stream) {
    const float* x     = (const float*)d_in[0];
    const int*   ei    = (const int*)d_in[1];
    const float* ea    = (const float*)d_in[2];
    const float* g     = (const float*)d_in[3];
    const float* mu    = (const float*)d_in[4];
    const float* sigma = (const float*)d_in[5];
    const float* root  = (const float*)d_in[6];
    const float* bias  = (const float*)d_in[7];
    float* out = (float*)d_out;

    char* ws = (char*)d_ws;
    const size_t aggmh_bytes  = (size_t)N_NODES * 256 * sizeof(_Float16); // 25.6 MB
    const size_t packed_bytes = (size_t)N_EDGES * sizeof(int2);           //  6.4 MB
    const size_t rank_bytes   = (size_t)N_EDGES * sizeof(int);            //  3.2 MB
    const size_t wfrag_bytes  = (size_t)2048 * 8 * sizeof(_Float16);      //  32 KB
    _Float16* aggmh = (_Float16*)ws;
    int2*     packed = (int2*)(ws + aggmh_bytes);
    int*      rank   = (int*)(ws + aggmh_bytes + packed_bytes);
    _Float16* wfrag  = (_Float16*)(ws + aggmh_bytes + packed_bytes + rank_bytes);
    int* counts = (int*)(ws + aggmh_bytes + packed_bytes + rank_bytes + wfrag_bytes);
    int* off    = counts + N_NODES;           // N_NODES+1 entries
    int* bsum   = off + N_NODES + 1;
    int* boff   = bsum + NB_SCAN;

    hipMemsetAsync(counts, 0, N_NODES * sizeof(int), stream);

    hist_kernel<<<(N_EDGES + 255) / 256, 256, 0, stream>>>(ei, counts, rank);
    scanA_kernel<<<NB_SCAN, 256, 0, stream>>>(counts, bsum);
    scanB_kernel<<<1, 256, 0, stream>>>(bsum, boff);
    scanC_kernel<<<NB_SCAN, 256, 0, stream>>>(counts, boff, off);
    scatter_kernel<<<(N_EDGES + 255) / 256, 256, 0, stream>>>(ei, ea, off, rank, packed);
    wprep_kernel<<<8, 256, 0, stream>>>(g, root, wfrag);
    aggregate_kernel<<<(N_NODES + 3) / 4, 256, 0, stream>>>(x, packed, off, mu, sigma, aggmh);
    mfma_gemm_kernel<<<(N_NODES + 63) / 64, 256, 0, stream>>>(aggmh, wfrag, x, bias, out);
}